// Round 5
// baseline (690.832 us; speedup 1.0000x reference)
//
#include <hip/hip_runtime.h>
#include <math.h>

#define NEXP 8
#define TILE 128
#define BK 32

typedef __attribute__((ext_vector_type(8))) short short8;
typedef __attribute__((ext_vector_type(4))) float float4v;

__device__ __forceinline__ unsigned short f2bf(float f) {
  union { float f; unsigned u; } v; v.f = f;
  unsigned r = v.u + 0x7FFFu + ((v.u >> 16) & 1u);  // RNE
  return (unsigned short)(r >> 16);
}
__device__ __forceinline__ unsigned pack2(float a, float b) {
  return (unsigned)f2bf(a) | ((unsigned)f2bf(b) << 16);
}

// async global->LDS, 16B per lane. LDS dst is wave-uniform base + lane*16.
__device__ __forceinline__ void gll16(const void* g, void* l) {
  __builtin_amdgcn_global_load_lds(
      (const __attribute__((address_space(1))) unsigned int*)(unsigned long long)(uintptr_t)g,
      (__attribute__((address_space(3))) unsigned int*)(unsigned)(uintptr_t)l,
      16, 0, 0);
}

// streaming pack of one 128-row x 1024-col fp32 slab into 32 fragment-major
// bf16 panels: [chunk r>>4][colgrp c>>3][row r&15][8], panel = 4096 shorts.
__device__ __forceinline__ void pack_slab(
    const float* __restrict__ src, unsigned short* __restrict__ dst,
    int e, int rt, int cc, int K, int n_rt, int n_ks, int tid) {
  const int row = tid >> 1, half = tid & 1;
  const float* sb = src + ((size_t)(e * n_rt + rt) * 128 + row) * K + cc * 1024 + half * 16;
  unsigned short* db = dst + ((size_t)(e * n_rt + rt) * n_ks + cc * 32) * 4096
                           + (row >> 4) * 512 + (row & 15) * 8 + half * 256;
#pragma unroll 4
  for (int kk = 0; kk < 32; ++kk) {
    const float4* s = (const float4*)(sb + kk * 32);
    float4 v0 = s[0], v1 = s[1], v2 = s[2], v3 = s[3];
    uint4 o0, o1;
    o0.x = pack2(v0.x, v0.y); o0.y = pack2(v0.z, v0.w);
    o0.z = pack2(v1.x, v1.y); o0.w = pack2(v1.z, v1.w);
    o1.x = pack2(v2.x, v2.y); o1.y = pack2(v2.z, v2.w);
    o1.z = pack2(v3.x, v3.y); o1.w = pack2(v3.z, v3.w);
    unsigned short* d = db + kk * 4096;
    *(uint4*)d = o0;
    *(uint4*)(d + 128) = o1;
  }
}

// ---------------- fused prep: pack gw/uw(/dw) + x->bf16 + routing ----------------
// 1D grid: [768 pack blocks][nconv convert blocks][nrout routing blocks]
__global__ __launch_bounds__(256) void prep_kernel(
    const float* __restrict__ gw, const float* __restrict__ uw,
    const float* __restrict__ dw, const float* __restrict__ x,
    const float* __restrict__ cw, const float* __restrict__ cbv,
    const float* __restrict__ wealth,
    unsigned short* __restrict__ gwp, unsigned short* __restrict__ uwp,
    unsigned short* __restrict__ dwp, unsigned short* __restrict__ xb,
    int* __restrict__ plist, int* __restrict__ counts, float* __restrict__ w_rt,
    int T, int H, int I, int ndw, int nconv, int n4) {
  const int b = blockIdx.x;
  const int tid = threadIdx.x;
  const int npack = 512 + ndw;
  if (b < npack) {
    if (b < 256) {
      pack_slab(gw, gwp, b >> 5, b & 31, 0, H, 32, 32, tid);
    } else if (b < 512) {
      int i = b - 256;
      pack_slab(uw, uwp, i >> 5, i & 31, 0, H, 32, 32, tid);
    } else {
      int i = b - 512;           // dw: [E][H][I]; 8 row-tiles x 4 col-chunks
      pack_slab(dw, dwp, i >> 5, (i & 31) >> 2, i & 3, I, 8, 128, tid);
    }
    return;
  }
  if (b < npack + nconv) {
    // ---- x -> bf16, grid-stride ----
    int i = (b - npack) * 256 + tid;
    int stride = nconv * 256;
    for (; i < n4; i += stride) {
      float4 v = ((const float4*)x)[i];
      uint2 o; o.x = pack2(v.x, v.y); o.y = pack2(v.z, v.w);
      ((uint2*)xb)[i] = o;
    }
    return;
  }
  // ---- routing: one wave per token (fp32, selection-exact) ----
  int t = (b - npack - nconv) * 4 + (tid >> 6);
  if (t >= T) return;
  const int lane = tid & 63;
  const float4* x4 = (const float4*)(x + (size_t)t * H);
  const float4* c4 = (const float4*)cw;
  const int h4n = H >> 2;
  float acc[NEXP];
#pragma unroll
  for (int e = 0; e < NEXP; ++e) acc[e] = 0.f;
  for (int h = lane; h < h4n; h += 64) {
    float4 xv = x4[h];
#pragma unroll
    for (int e = 0; e < NEXP; ++e) {
      float4 cv = c4[(size_t)e * h4n + h];
      acc[e] += xv.x * cv.x + xv.y * cv.y + xv.z * cv.z + xv.w * cv.w;
    }
  }
#pragma unroll
  for (int e = 0; e < NEXP; ++e) {
    float v = acc[e];
#pragma unroll
    for (int off = 32; off > 0; off >>= 1) v += __shfl_down(v, off, 64);
    acc[e] = v;
  }
  if (lane == 0) {
    float bids[NEXP];
#pragma unroll
    for (int e = 0; e < NEXP; ++e) {
      float lg = acc[e] + cbv[e];
      float c = 1.f / (1.f + expf(-lg));
      bids[e] = c * wealth[e];
    }
    int i0 = 0;
    for (int e = 1; e < NEXP; ++e) if (bids[e] > bids[i0]) i0 = e;  // ties -> lower idx
    int i1 = (i0 == 0) ? 1 : 0;
    for (int e = 0; e < NEXP; ++e) if (e != i0 && bids[e] > bids[i1]) i1 = e;
    float ex = expf(bids[i1] - bids[i0]);
    float wsum = 1.f + ex;
    w_rt[2 * t]     = 1.f / wsum;
    w_rt[2 * t + 1] = ex / wsum;
    int p0 = atomicAdd(&counts[i0], 1);
    plist[i0 * T + p0] = 2 * t;
    int p1 = atomicAdd(&counts[i1], 1);
    plist[i1 * T + p1] = 2 * t + 1;
  }
}

// fallback: pack dw after gateup when dwp must alias gwp (small workspace)
__global__ __launch_bounds__(256) void pack_dw_kernel(
    const float* __restrict__ dw, unsigned short* __restrict__ dwp, int I) {
  int i = blockIdx.x;
  pack_slab(dw, dwp, i >> 5, (i & 31) >> 2, i & 3, I, 8, 128, threadIdx.x);
}

// ---------------- gate+up fused GEMM: 2-phase dbuf (round-1 verified) ----------------
__global__ __launch_bounds__(256, 2) void gateup_kernel(
    const unsigned short* __restrict__ xb, const unsigned short* __restrict__ gwp,
    const unsigned short* __restrict__ uwp, const int* __restrict__ plist,
    const int* __restrict__ counts, unsigned short* __restrict__ act,
    int T, int H, int I) {
  const int nx = gridDim.x, ny = gridDim.y, nz = gridDim.z;
  int rt = blockIdx.x, it = blockIdx.y, e = blockIdx.z;
  {
    int nwg = nx * ny * nz;
    if (((nwg & 7) == 0) && (((nwg >> 3) % nx) == 0)) {
      int orig = blockIdx.x + nx * (blockIdx.y + ny * blockIdx.z);
      int idx = orig >> 3, xcd = orig & 7;
      int q = idx / nx;
      rt = idx - q * nx;
      int chunk = q * 8 + xcd;
      it = chunk % ny;
      e = chunk / ny;
    }
  }
  const int cnt = counts[e];
  const int row0 = rt * TILE;
  if (row0 >= cnt) return;
  const int nks = H / BK;  // 32

  __shared__ __align__(16) unsigned short As[2][TILE * BK];
  __shared__ __align__(16) unsigned short Bg[2][TILE * BK];
  __shared__ __align__(16) unsigned short Bu[2][TILE * BK];

  const int tid = threadIdx.x, lane = tid & 63, wv = tid >> 6;
  const int wm = wv >> 1, wn = wv & 1;
  const int quad = lane >> 4, l15 = lane & 15;

  int ri0 = row0 + wv * 32 + l15;
  int ri1 = ri0 + 16;
  if (ri0 >= cnt) ri0 = cnt - 1;
  if (ri1 >= cnt) ri1 = cnt - 1;
  const unsigned short* a0 = xb + (size_t)(plist[e * T + ri0] >> 1) * H + quad * 8;
  const unsigned short* a1 = xb + (size_t)(plist[e * T + ri1] >> 1) * H + quad * 8;

  const size_t pan = ((size_t)(e * ny + it) * nks) * (TILE * BK);
  const unsigned short* g0 = gwp + pan + (size_t)wv * 1024 + (size_t)lane * 8;
  const unsigned short* u0 = uwp + pan + (size_t)wv * 1024 + (size_t)lane * 8;

  float4v accg[4][4], accu[4][4];
#pragma unroll
  for (int a = 0; a < 4; ++a)
#pragma unroll
    for (int b = 0; b < 4; ++b) {
      float4v z = {0.f, 0.f, 0.f, 0.f};
      accg[a][b] = z; accu[a][b] = z;
    }

  auto stage = [&](int kk, int b) {
    unsigned short* lA = &As[b][wv * 1024];
    unsigned short* lG = &Bg[b][wv * 1024];
    unsigned short* lU = &Bu[b][wv * 1024];
    size_t ka = (size_t)kk * BK;
    size_t kb = (size_t)kk * (TILE * BK);
    gll16(a0 + ka, lA);       gll16(a1 + ka, lA + 512);
    gll16(g0 + kb, lG);       gll16(g0 + kb + 512, lG + 512);
    gll16(u0 + kb, lU);       gll16(u0 + kb + 512, lU + 512);
  };

  stage(0, 0);
  __syncthreads();
  for (int k = 0; k < nks; ++k) {
    const int cb = k & 1;
    if (k + 1 < nks) stage(k + 1, cb ^ 1);
    short8 af[4], bgf[4], buf_[4];
#pragma unroll
    for (int mi = 0; mi < 4; ++mi)
      af[mi] = *(const short8*)(&As[cb][(wm * 4 + mi) * 512 + quad * 128 + l15 * 8]);
#pragma unroll
    for (int ni = 0; ni < 4; ++ni) {
      bgf[ni]  = *(const short8*)(&Bg[cb][(wn * 4 + ni) * 512 + quad * 128 + l15 * 8]);
      buf_[ni] = *(const short8*)(&Bu[cb][(wn * 4 + ni) * 512 + quad * 128 + l15 * 8]);
    }
#pragma unroll
    for (int mi = 0; mi < 4; ++mi)
#pragma unroll
      for (int ni = 0; ni < 4; ++ni) {
        accg[mi][ni] = __builtin_amdgcn_mfma_f32_16x16x32_bf16(af[mi], bgf[ni], accg[mi][ni], 0, 0, 0);
        accu[mi][ni] = __builtin_amdgcn_mfma_f32_16x16x32_bf16(af[mi], buf_[ni], accu[mi][ni], 0, 0, 0);
      }
    __syncthreads();
  }

  // epilogue: C/D layout col=lane&15, row=quad*4+reg
#pragma unroll
  for (int mi = 0; mi < 4; ++mi) {
    int rbase = wm * 64 + mi * 16 + quad * 4;
#pragma unroll
    for (int r = 0; r < 4; ++r) {
      int grow = row0 + rbase + r;
      if (grow < cnt) {
        int p = plist[e * T + grow];
        size_t base = (size_t)p * I + it * TILE + wn * 64 + l15;
#pragma unroll
        for (int ni = 0; ni < 4; ++ni) {
          float g = accg[mi][ni][r];
          float u = accu[mi][ni][r];
          float s = g / (1.f + __expf(-g)) * u;  // silu(g)*u
          act[base + ni * 16] = f2bf(s);
        }
      }
    }
  }
}

// ---------------- down GEMM: 2-phase dbuf (round-1 verified), split-K=2 ----------------
__global__ __launch_bounds__(256, 2) void down_kernel(
    const unsigned short* __restrict__ act, const unsigned short* __restrict__ dwp,
    const int* __restrict__ plist, const int* __restrict__ counts,
    float* __restrict__ part, int T, int H, int I) {
  const int nx = gridDim.x, ny = gridDim.y, nz = gridDim.z;
  int rt = blockIdx.x, ht = blockIdx.y, zz = blockIdx.z;
  {
    int nwg = nx * ny * nz;
    if (((nwg & 7) == 0) && (((nwg >> 3) % nx) == 0)) {
      int orig = blockIdx.x + nx * (blockIdx.y + ny * blockIdx.z);
      int idx = orig >> 3, xcd = orig & 7;
      int q = idx / nx;
      rt = idx - q * nx;
      int chunk = q * 8 + xcd;
      ht = chunk % ny;
      zz = chunk / ny;
    }
  }
  const int e = zz >> 1, split = zz & 1;
  const int cnt = counts[e];
  const int row0 = rt * TILE;
  if (row0 >= cnt) return;
  const int nks_tot = I / BK;      // 128
  const int nks = nks_tot >> 1;    // 64 per split
  const int k0 = split * nks;

  __shared__ __align__(16) unsigned short As[2][TILE * BK];
  __shared__ __align__(16) unsigned short Bs[2][TILE * BK];

  const int tid = threadIdx.x, lane = tid & 63, wv = tid >> 6;
  const int wm = wv >> 1, wn = wv & 1;
  const int quad = lane >> 4, l15 = lane & 15;

  int ri0 = row0 + wv * 32 + l15;
  int ri1 = ri0 + 16;
  if (ri0 >= cnt) ri0 = cnt - 1;
  if (ri1 >= cnt) ri1 = cnt - 1;
  const unsigned short* a0 = act + (size_t)plist[e * T + ri0] * I + k0 * BK + quad * 8;
  const unsigned short* a1 = act + (size_t)plist[e * T + ri1] * I + k0 * BK + quad * 8;

  const size_t pan = ((size_t)(e * ny + ht) * nks_tot + k0) * (TILE * BK);
  const unsigned short* b0 = dwp + pan + (size_t)wv * 1024 + (size_t)lane * 8;

  float4v acc[4][4];
#pragma unroll
  for (int a = 0; a < 4; ++a)
#pragma unroll
    for (int b = 0; b < 4; ++b) { float4v z = {0.f, 0.f, 0.f, 0.f}; acc[a][b] = z; }

  auto stage = [&](int kk, int b) {
    unsigned short* lA = &As[b][wv * 1024];
    unsigned short* lB = &Bs[b][wv * 1024];
    size_t ka = (size_t)kk * BK;
    size_t kb = (size_t)kk * (TILE * BK);
    gll16(a0 + ka, lA);  gll16(a1 + ka, lA + 512);
    gll16(b0 + kb, lB);  gll16(b0 + kb + 512, lB + 512);
  };

  stage(0, 0);
  __syncthreads();
  for (int k = 0; k < nks; ++k) {
    const int cb = k & 1;
    if (k + 1 < nks) stage(k + 1, cb ^ 1);
    short8 af[4], bf[4];
#pragma unroll
    for (int mi = 0; mi < 4; ++mi)
      af[mi] = *(const short8*)(&As[cb][(wm * 4 + mi) * 512 + quad * 128 + l15 * 8]);
#pragma unroll
    for (int ni = 0; ni < 4; ++ni)
      bf[ni] = *(const short8*)(&Bs[cb][(wn * 4 + ni) * 512 + quad * 128 + l15 * 8]);
#pragma unroll
    for (int mi = 0; mi < 4; ++mi)
#pragma unroll
      for (int ni = 0; ni < 4; ++ni)
        acc[mi][ni] = __builtin_amdgcn_mfma_f32_16x16x32_bf16(af[mi], bf[ni], acc[mi][ni], 0, 0, 0);
    __syncthreads();
  }

#pragma unroll
  for (int mi = 0; mi < 4; ++mi) {
    int rbase = wm * 64 + mi * 16 + quad * 4;
#pragma unroll
    for (int r = 0; r < 4; ++r) {
      int grow = row0 + rbase + r;
      if (grow < cnt) {
        int p = plist[e * T + grow];
        size_t base = ((size_t)split * 2 * T + p) * H + ht * TILE + wn * 64 + l15;
#pragma unroll
        for (int ni = 0; ni < 4; ++ni)
          part[base + ni * 16] = acc[mi][ni][r];
      }
    }
  }
}

// ---------------- combine: out = w0*(p00+p10) + w1*(p01+p11) ----------------
__global__ __launch_bounds__(256) void combine_kernel(
    const float* __restrict__ part, const float* __restrict__ w_rt,
    float* __restrict__ out, int T, int H) {
  int h4 = H >> 2;
  int n4 = T * h4;
  int i = blockIdx.x * 256 + threadIdx.x;
  if (i >= n4) return;
  int t = i / h4;
  int c = i - t * h4;
  float w0 = w_rt[2 * t], w1 = w_rt[2 * t + 1];
  size_t splitoff = (size_t)2 * T * H / 4;  // in float4 units
  const float4* pa = (const float4*)(part + (size_t)(2 * t) * H);
  const float4* pb = (const float4*)(part + (size_t)(2 * t + 1) * H);
  float4 a0 = pa[c], a1 = pa[c + splitoff];
  float4 b0 = pb[c], b1 = pb[c + splitoff];
  float4 o;
  o.x = w0 * (a0.x + a1.x) + w1 * (b0.x + b1.x);
  o.y = w0 * (a0.y + a1.y) + w1 * (b0.y + b1.y);
  o.z = w0 * (a0.z + a1.z) + w1 * (b0.z + b1.z);
  o.w = w0 * (a0.w + a1.w) + w1 * (b0.w + b1.w);
  ((float4*)(out + (size_t)t * H))[c] = o;
}

extern "C" void kernel_launch(void* const* d_in, const int* in_sizes, int n_in,
                              void* d_out, int out_size, void* d_ws, size_t ws_size,
                              hipStream_t stream) {
  const float* x      = (const float*)d_in[0];
  const float* cw     = (const float*)d_in[1];
  const float* cb     = (const float*)d_in[2];
  const float* gw     = (const float*)d_in[3];
  const float* uw     = (const float*)d_in[4];
  const float* dw     = (const float*)d_in[5];
  const float* wealth = (const float*)d_in[6];
  float* out = (float*)d_out;

  const int H = in_sizes[1] / NEXP;          // conf_w (E,H)
  const int T = in_sizes[0] / H;             // hidden (B*S,H)
  const int I = in_sizes[3] / (NEXP * H);    // gate_w (E,I,H)

  char* ws = (char*)d_ws;
  size_t off = 0;
  unsigned short* xb  = (unsigned short*)(ws + off); off += (size_t)T * H * 2;
  unsigned short* act = (unsigned short*)(ws + off); off += (size_t)2 * T * I * 2;
  float* part = (float*)(ws + off); off += (size_t)2 * 2 * T * H * 4;  // split-K=2
  unsigned short* gwp = (unsigned short*)(ws + off); off += (size_t)NEXP * I * H * 2;
  unsigned short* uwp = (unsigned short*)(ws + off); off += (size_t)NEXP * I * H * 2;
  int* plist = (int*)(ws + off); off += (size_t)NEXP * T * 4;
  float* w_rt = (float*)(ws + off); off += (size_t)T * 2 * 4;
  int* counts = (int*)(ws + off); off += NEXP * 4;
  // separate dwp if workspace allows; else alias gwp and pack dw after gateup
  size_t dwp_need = off + (size_t)NEXP * H * I * 2;
  int sep = (ws_size >= dwp_need) ? 1 : 0;
  unsigned short* dwp = sep ? (unsigned short*)(ws + off) : gwp;

  hipMemsetAsync(counts, 0, NEXP * sizeof(int), stream);

  int n4 = (T * H) / 4;
  int nconv = 256;
  int nrout = (T + 3) / 4;
  int ndw = sep ? 256 : 0;
  int nprep = 512 + ndw + nconv + nrout;
  prep_kernel<<<nprep, 256, 0, stream>>>(gw, uw, dw, x, cw, cb, wealth,
                                         gwp, uwp, dwp, xb, plist, counts, w_rt,
                                         T, H, I, ndw, nconv, n4);

  int ttiles = (T + TILE - 1) / TILE;
  dim3 g1(ttiles, I / TILE, NEXP);
  gateup_kernel<<<g1, 256, 0, stream>>>(xb, gwp, uwp, plist, counts, act, T, H, I);

  if (!sep) pack_dw_kernel<<<256, 256, 0, stream>>>(dw, dwp, I);

  dim3 g2(ttiles, H / TILE, NEXP * 2);  // z = expert*2 + ksplit
  down_kernel<<<g2, 256, 0, stream>>>(act, dwp, plist, counts, part, T, H, I);

  combine_kernel<<<(n4 + 255) / 256, 256, 0, stream>>>(part, w_rt, out, T, H);
}